// Round 3
// baseline (19353.693 us; speedup 1.0000x reference)
//
#include <hip/hip_runtime.h>
#include <hip/hip_bf16.h>
#include <hip/hip_cooperative_groups.h>
namespace cg = cooperative_groups;

// RSSM scan: B=512, T=64, STOCH=32, DETER=512, HIDDEN=512, ACT=12, EMBED=1024
// out per (b,t): [ostoch32, om32, ostd32, pstoch32, pm32, ps32, deter512] = 704 f32

typedef __attribute__((ext_vector_type(8))) short bf16x8;
typedef __attribute__((ext_vector_type(4))) float f32x4;

static __device__ __forceinline__ short f2b(float x){
  __hip_bfloat16 h = __float2bfloat16(x);
  return *reinterpret_cast<short*>(&h);
}
static __device__ __forceinline__ float b2f(short s){
  __hip_bfloat16 h = *reinterpret_cast<__hip_bfloat16*>(&s);
  return __bfloat162float(h);
}
static __device__ __forceinline__ float softplusf_(float x){
  return (x > 20.f) ? x : log1pf(expf(x));
}

// block reduction over 256 threads; leading sync protects LDS reuse
static __device__ __forceinline__ float bsum(float v, float* red){
  int tid = threadIdx.x;
  __syncthreads();
  red[tid] = v; __syncthreads();
  for(int s = 128; s>0; s>>=1){
    if(tid < s) red[tid] += red[tid+s];
    __syncthreads();
  }
  return red[0];
}

static __device__ __forceinline__ void stage8f(short* dst, const float* src){
  float4 f0 = *reinterpret_cast<const float4*>(src);
  float4 f1 = *reinterpret_cast<const float4*>(src+4);
  bf16x8 v;
  v[0]=f2b(f0.x); v[1]=f2b(f0.y); v[2]=f2b(f0.z); v[3]=f2b(f0.w);
  v[4]=f2b(f1.x); v[5]=f2b(f1.y); v[6]=f2b(f1.z); v[7]=f2b(f1.w);
  *reinterpret_cast<bf16x8*>(dst) = v;
}

// 64x64 output tile GEMM piece, 4 waves (2x2), wave tile 32x32, K = nkt*64.
// AF32: A is f32 in global (converted on stage); else bf16 (short).
template<bool AF32>
static __device__ __forceinline__ void gemm_tile(
    const void* __restrict__ Ap, int lda,
    const short* __restrict__ Bp, int ldb,
    float* __restrict__ Cp, int ldc,
    int mP, int nP, int kA0, int kB0, int nkt,
    short (*As)[72], short (*Bs)[72])
{
  int tid = threadIdx.x, lane = tid&63, wid = tid>>6;
  int wm = (wid>>1)*32, wn = (wid&1)*32;
  f32x4 acc[2][2] = {};
  for(int kt=0; kt<nkt; kt++){
    #pragma unroll
    for(int c=0;c<2;c++){
      int idx = tid + c*256; int r = idx>>3, kc = (idx&7)*8;
      if(AF32){
        stage8f(&As[r][kc], (const float*)Ap + (size_t)(mP+r)*lda + kA0 + kt*64 + kc);
      } else {
        *(int4*)&As[r][kc] = *(const int4*)((const short*)Ap + (size_t)(mP+r)*lda + kA0 + kt*64 + kc);
      }
      *(int4*)&Bs[r][kc] = *(const int4*)&Bp[(size_t)(nP+r)*ldb + kB0 + kt*64 + kc];
    }
    __syncthreads();
    #pragma unroll
    for(int ks=0; ks<64; ks+=32){
      int ko = ks + 8*(lane>>4);
      bf16x8 a0 = *(const bf16x8*)&As[wm +      (lane&15)][ko];
      bf16x8 a1 = *(const bf16x8*)&As[wm + 16 + (lane&15)][ko];
      bf16x8 b0 = *(const bf16x8*)&Bs[wn +      (lane&15)][ko];
      bf16x8 b1 = *(const bf16x8*)&Bs[wn + 16 + (lane&15)][ko];
      acc[0][0] = __builtin_amdgcn_mfma_f32_16x16x32_bf16(a0,b0,acc[0][0],0,0,0);
      acc[0][1] = __builtin_amdgcn_mfma_f32_16x16x32_bf16(a0,b1,acc[0][1],0,0,0);
      acc[1][0] = __builtin_amdgcn_mfma_f32_16x16x32_bf16(a1,b0,acc[1][0],0,0,0);
      acc[1][1] = __builtin_amdgcn_mfma_f32_16x16x32_bf16(a1,b1,acc[1][1],0,0,0);
    }
    __syncthreads();
  }
  int r0 = (lane>>4)*4, c0 = lane&15;
  for(int mi=0;mi<2;mi++) for(int ni=0;ni<2;ni++){
    int row = mP + wm + mi*16 + r0, col = nP + wn + ni*16 + c0;
    #pragma unroll
    for(int r=0;r<4;r++) Cp[(size_t)(row+r)*ldc + col] = acc[mi][ni][r];
  }
}

// ---------------- phase bodies (shared by coop kernel and fallback) ----------
static __device__ __forceinline__ void dev_p1(int task,
    const short* xdeter, const short* wgruT, float* parts,
    short (*As)[72], short (*Bs)[72]){
  int mP = (task&7)*64, nP = (task>>3)*64;
  gemm_tile<false>(xdeter, 1024, wgruT, 1024, parts, 1536, mP, nP, 0, 0, 16, As, Bs);
}

static __device__ __forceinline__ void dev_p2(int b, int t,
    const float* parts, const float* gg, const float* gb,
    const float* is_first, const float* deter0,
    float* deterF, short* deterB, float* out, float* red){
  int tid = threadIdx.x;
  const float* p = parts + (size_t)b*1536;
  float v[6]; float sv=0.f, sqv=0.f;
  #pragma unroll
  for(int k=0;k<6;k++){ float x = p[tid+k*256]; v[k]=x; sv+=x; sqv+=x*x; }
  float sum = bsum(sv, red);
  float ssq = bsum(sqv, red);
  float mu = sum/1536.f, var = ssq/1536.f - mu*mu;
  float rstd = rsqrtf(var + 1e-3f);
  float f = is_first[b*64 + t];
  for(int jj=0;jj<2;jj++){
    int j = tid + jj*256;
    float xr = (v[jj]  -mu)*rstd*gg[j]       + gb[j];
    float xc = (v[2+jj]-mu)*rstd*gg[512+j]   + gb[512+j];
    float xu = (v[4+jj]-mu)*rstd*gg[1024+j]  + gb[1024+j];
    float r = 1.f/(1.f+expf(-xr));
    float c = tanhf(r*xc);
    float u = 1.f/(1.f+expf(-(xu-1.f)));
    float dp = deterF[b*512+j]*(1.f-f) + deter0[j]*f;
    float dn = u*c + (1.f-u)*dp;
    deterF[b*512+j] = dn;
    deterB[b*512+j] = f2b(dn);
    out[(size_t)b*45056 + t*704 + 192 + j] = dn;
  }
}

static __device__ __forceinline__ void dev_p3(int task, int t,
    const short* deterB, const float* embed,
    const short* wobsDT, const short* wobsET, float* xopreP,
    short (*As)[72], short (*Bs)[72]){
  int s = task/64, tile = task%64;
  int mP = (tile&7)*64, nP = (tile>>3)*64;
  if(s == 0){
    gemm_tile<false>(deterB, 512, wobsDT, 512, xopreP, 512, mP, nP, 0, 0, 8, As, Bs);
  } else if(s == 1){
    gemm_tile<true>(embed + (size_t)t*1024, 65536, wobsET, 1024,
                    xopreP + 262144, 512, mP, nP, 0, 0, 8, As, Bs);
  } else {
    gemm_tile<true>(embed + (size_t)t*1024, 65536, wobsET, 1024,
                    xopreP + 524288, 512, mP, nP, 512, 512, 8, As, Bs);
  }
}

static __device__ __forceinline__ void dev_p4(int b, int t,
    const float* xopreP, const float* og, const float* ob,
    const float* w_ostat, const float* b_ostat,
    const float* eps_post, const float* is_first,
    const float* action, const float* w_in,
    const float* ig, const float* ib,
    const float* stoch0, const float* deter0,
    const float* deterF, short* xdeter, float* out, float* S){
  int tid = threadIdx.x;
  float* red = S;              // 256
  float* xo  = S + 256;        // 512
  float (*psh)[64] = (float(*)[64])(S + 768); // 4*64
  float* sol = S + 1024;       // 64
  float* st  = S + 1088;       // 32
  float* al  = S + 1120;       // 12
  float xv[2];
  for(int i=0;i<2;i++){
    int h = tid + i*256;
    float a = xopreP[(size_t)b*512 + h]
            + xopreP[262144 + (size_t)b*512 + h]
            + xopreP[524288 + (size_t)b*512 + h];
    xv[i] = a;
  }
  float sum = bsum(xv[0]+xv[1], red);
  float sq  = bsum(xv[0]*xv[0]+xv[1]*xv[1], red);
  float mu = sum/512.f, var = sq/512.f - mu*mu;
  float rstd = rsqrtf(var + 1e-3f);
  for(int i=0;i<2;i++){
    int h = tid + i*256;
    float xn = (xv[i]-mu)*rstd*og[h]+ob[h];
    xo[h] = xn/(1.f+expf(-xn));
  }
  __syncthreads();
  { int p = tid>>6, n = tid&63; float a = 0.f;
    for(int k=p*128; k<p*128+128; k++) a += xo[k]*w_ostat[k*64+n];
    psh[p][n] = a; }
  __syncthreads();
  if(tid < 64) sol[tid] = psh[0][tid]+psh[1][tid]+psh[2][tid]+psh[3][tid] + b_ostat[tid];
  __syncthreads();
  float fn = (t < 63) ? is_first[b*64 + t + 1] : 0.f;
  if(tid < 32){
    float om = sol[tid];
    float osd = softplusf_(sol[32+tid]) + 0.1f;
    float eo = eps_post[(size_t)(b*64+t)*32 + tid];
    float ost = om + osd*eo;
    size_t base = (size_t)b*45056 + t*704;
    out[base+tid] = ost; out[base+32+tid] = om; out[base+64+tid] = osd;
    st[tid] = ost*(1.f-fn) + stoch0[tid]*fn;
  }
  if(tid < 12 && t < 63) al[tid] = action[(size_t)(b*64+t+1)*12 + tid]*(1.f-fn);
  __syncthreads();
  if(t < 63){
    float xp[2];
    for(int i=0;i<2;i++){
      int h = tid + i*256; float a = 0.f;
      for(int k=0;k<32;k++) a += st[k]*w_in[k*512+h];
      for(int k=0;k<12;k++) a += al[k]*w_in[(32+k)*512+h];
      xp[i] = a;
    }
    float s2 = bsum(xp[0]+xp[1], red);
    float q2 = bsum(xp[0]*xp[0]+xp[1]*xp[1], red);
    float mu2 = s2/512.f, var2 = q2/512.f - mu2*mu2;
    float rstd2 = rsqrtf(var2 + 1e-3f);
    for(int i=0;i<2;i++){
      int h = tid + i*256;
      float xn = (xp[i]-mu2)*rstd2*ig[h]+ib[h];
      float xs = xn/(1.f+expf(-xn));
      xdeter[(size_t)b*1024 + h] = f2b(xs);
      xdeter[(size_t)b*1024 + 512 + h] = f2b(deterF[b*512+h]*(1.f-fn) + deter0[h]*fn);
    }
  }
  __syncthreads(); // protect shared S before next caller reuse
}

// ---------------- weight transpose/convert (one-time per call) ----------------
__global__ __launch_bounds__(256) void k_wt(const float* __restrict__ wg,
    const float* __restrict__ wo, const float* __restrict__ wou,
    short* __restrict__ wgruT, short* __restrict__ wobsDT,
    short* __restrict__ wobsET, short* __restrict__ woutT){
  int i = blockIdx.x*256 + threadIdx.x;
  if(i < 1572864){ int n = i>>10, k = i&1023; wgruT[i] = f2b(wg[k*1536+n]); return; }
  i -= 1572864;
  if(i < 262144){ int n = i>>9, k = i&511; wobsDT[i] = f2b(wo[k*512+n]); return; }
  i -= 262144;
  if(i < 524288){ int n = i>>10, k = i&1023; wobsET[i] = f2b(wo[(512+k)*512+n]); return; }
  i -= 524288;
  { int n = i>>9, k = i&511; woutT[i] = f2b(wou[k*512+n]); }
}

// ---------------- init: deter0 = tanh(W_init); stoch0 = img_mean(deter0) -----
__global__ __launch_bounds__(512) void k_init(const float* __restrict__ W_init,
    const float* __restrict__ w_out, const float* __restrict__ og, const float* __restrict__ ob,
    const float* __restrict__ w_ims, const float* __restrict__ b_ims,
    float* __restrict__ deter0, float* __restrict__ stoch0){
  __shared__ float d0[512]; __shared__ float red[512]; __shared__ float x2[512];
  int tid = threadIdx.x;
  float d = tanhf(W_init[tid]); d0[tid] = d; deter0[tid] = d; __syncthreads();
  float s = 0.f;
  for(int k=0;k<512;k++) s += d0[k]*w_out[k*512+tid];
  // 512-thread bsum
  red[tid] = s; __syncthreads();
  for(int ss=256; ss>0; ss>>=1){ if(tid<ss) red[tid]+=red[tid+ss]; __syncthreads(); }
  float sum = red[0]; __syncthreads();
  red[tid] = s*s; __syncthreads();
  for(int ss=256; ss>0; ss>>=1){ if(tid<ss) red[tid]+=red[tid+ss]; __syncthreads(); }
  float sq = red[0];
  float mu = sum/512.f, var = sq/512.f - mu*mu;
  float rstd = rsqrtf(var + 1e-3f);
  float xn = (s-mu)*rstd*og[tid] + ob[tid];
  float xs = xn/(1.f+expf(-xn));
  x2[tid] = xs; __syncthreads();
  if(tid < 32){
    float acc = b_ims[tid];
    for(int k=0;k<512;k++) acc += x2[k]*w_ims[k*64+tid];
    stoch0[tid] = acc;
  }
}

// ---------------- t=0 prologue: xdeter row = [x0 | deter0], deterF=deter0 ----
__global__ __launch_bounds__(256) void k_x0(const float* __restrict__ action,
    const float* __restrict__ is_first, const float* __restrict__ w_in,
    const float* __restrict__ ig, const float* __restrict__ ib,
    const float* __restrict__ deter0, const float* __restrict__ stoch0,
    short* __restrict__ xdeter, float* __restrict__ deterF){
  int b = blockIdx.x, tid = threadIdx.x;
  __shared__ float st[32]; __shared__ float al[12]; __shared__ float red[256];
  float f0 = is_first[b*64];
  if(tid < 32) st[tid] = stoch0[tid];
  if(tid < 12) al[tid] = action[b*768 + tid]*(1.f-f0);
  __syncthreads();
  float xp[2];
  for(int i=0;i<2;i++){
    int h = tid + i*256; float a = 0.f;
    for(int k=0;k<32;k++) a += st[k]*w_in[k*512+h];
    for(int k=0;k<12;k++) a += al[k]*w_in[(32+k)*512+h];
    xp[i] = a;
  }
  float sum = bsum(xp[0]+xp[1], red);
  float sq  = bsum(xp[0]*xp[0]+xp[1]*xp[1], red);
  float mu = sum/512.f, var = sq/512.f - mu*mu;
  float rstd = rsqrtf(var + 1e-3f);
  for(int i=0;i<2;i++){
    int h = tid + i*256;
    float xn = (xp[i]-mu)*rstd*ig[h]+ib[h];
    float xs = xn/(1.f+expf(-xn));
    xdeter[b*1024 + h] = f2b(xs);
    xdeter[b*1024 + 512 + h] = f2b(deter0[h]);
    deterF[b*512 + h] = deter0[h];
  }
}

// ---------------- persistent cooperative scan: 256 blocks x 256 thr ----------
__global__ void k_scan(
    short* __restrict__ xdeter, const short* __restrict__ wgruT,
    float* __restrict__ parts,
    const float* __restrict__ gg, const float* __restrict__ gb,
    const float* __restrict__ is_first, const float* __restrict__ deter0,
    float* __restrict__ deterF, short* __restrict__ deterB,
    const short* __restrict__ wobsDT, const short* __restrict__ wobsET,
    const float* __restrict__ embed, float* __restrict__ xopreP,
    const float* __restrict__ og, const float* __restrict__ ob,
    const float* __restrict__ w_ostat, const float* __restrict__ b_ostat,
    const float* __restrict__ eps_post, const float* __restrict__ action,
    const float* __restrict__ w_in, const float* __restrict__ ig,
    const float* __restrict__ ib, const float* __restrict__ stoch0,
    float* __restrict__ out)
{
  cg::grid_group grid = cg::this_grid();
  __shared__ __align__(16) char smem[2*64*72*2];
  short (*As)[72] = (short(*)[72])smem;
  short (*Bs)[72] = (short(*)[72])(smem + 64*72*2);
  float* S = (float*)smem;
  int bid = blockIdx.x;

  for(int t=0; t<64; t++){
    if(bid < 192) dev_p1(bid, xdeter, wgruT, parts, As, Bs);
    grid.sync();
    dev_p2(2*bid,   t, parts, gg, gb, is_first, deter0, deterF, deterB, out, S);
    dev_p2(2*bid+1, t, parts, gg, gb, is_first, deter0, deterF, deterB, out, S);
    grid.sync();
    if(bid < 192) dev_p3(bid, t, deterB, embed, wobsDT, wobsET, xopreP, As, Bs);
    grid.sync();
    dev_p4(2*bid,   t, xopreP, og, ob, w_ostat, b_ostat, eps_post, is_first,
           action, w_in, ig, ib, stoch0, deter0, deterF, xdeter, out, S);
    dev_p4(2*bid+1, t, xopreP, og, ob, w_ostat, b_ostat, eps_post, is_first,
           action, w_in, ig, ib, stoch0, deter0, deterF, xdeter, out, S);
    grid.sync();
  }
}

// ---------------- fallback per-step kernels (same device bodies) -------------
__global__ __launch_bounds__(256) void k_p1(const short* __restrict__ xdeter,
    const short* __restrict__ wgruT, float* __restrict__ parts){
  __shared__ __align__(16) short As[64][72];
  __shared__ __align__(16) short Bs[64][72];
  dev_p1(blockIdx.x, xdeter, wgruT, parts, As, Bs);
}
__global__ __launch_bounds__(256) void k_p2(const float* __restrict__ parts,
    const float* __restrict__ gg, const float* __restrict__ gb,
    const float* __restrict__ is_first, const float* __restrict__ deter0,
    float* __restrict__ deterF, short* __restrict__ deterB,
    float* __restrict__ out, int t){
  __shared__ float red[256];
  dev_p2(blockIdx.x, t, parts, gg, gb, is_first, deter0, deterF, deterB, out, red);
}
__global__ __launch_bounds__(256) void k_p3(const short* __restrict__ deterB,
    const float* __restrict__ embed, const short* __restrict__ wobsDT,
    const short* __restrict__ wobsET, float* __restrict__ xopreP, int t){
  __shared__ __align__(16) short As[64][72];
  __shared__ __align__(16) short Bs[64][72];
  dev_p3(blockIdx.x, t, deterB, embed, wobsDT, wobsET, xopreP, As, Bs);
}
__global__ __launch_bounds__(256) void k_p4(const float* __restrict__ xopreP,
    const float* __restrict__ og, const float* __restrict__ ob,
    const float* __restrict__ w_ostat, const float* __restrict__ b_ostat,
    const float* __restrict__ eps_post, const float* __restrict__ is_first,
    const float* __restrict__ action, const float* __restrict__ w_in,
    const float* __restrict__ ig, const float* __restrict__ ib,
    const float* __restrict__ stoch0, const float* __restrict__ deter0,
    const float* __restrict__ deterF, short* __restrict__ xdeter,
    float* __restrict__ out, int t){
  __shared__ float S[1152];
  dev_p4(blockIdx.x, t, xopreP, og, ob, w_ostat, b_ostat, eps_post, is_first,
         action, w_in, ig, ib, stoch0, deter0, deterF, xdeter, out, S);
}

// ---------------- deferred img-branch GEMM: x2pre = deter_all @ w_out --------
__global__ __launch_bounds__(256) void k_img(const float* __restrict__ outp,
    const short* __restrict__ WoT, short* __restrict__ x2pre){
  __shared__ __align__(16) short As[128][72];
  __shared__ __align__(16) short Bs[128][72];
  int tid = threadIdx.x, lane = tid&63, wid = tid>>6;
  int wm = (wid>>1)*64, wn = (wid&1)*64;
  int mP = blockIdx.x*128, nP = blockIdx.y*128;
  f32x4 acc[4][4] = {};
  for(int kt=0; kt<512; kt+=64){
    #pragma unroll
    for(int c=0;c<4;c++){
      int idx = tid + c*256; int r = idx>>3, kc = (idx&7)*8;
      stage8f(&As[r][kc], &outp[(size_t)(mP+r)*704 + 192 + kt + kc]);
      *(int4*)&Bs[r][kc] = *(const int4*)&WoT[(nP+r)*512 + kt + kc];
    }
    __syncthreads();
    #pragma unroll
    for(int ks=0; ks<64; ks+=32){
      int ko = ks + 8*(lane>>4);
      bf16x8 a[4], b[4];
      #pragma unroll
      for(int i=0;i<4;i++){
        a[i] = *(const bf16x8*)&As[wm + i*16 + (lane&15)][ko];
        b[i] = *(const bf16x8*)&Bs[wn + i*16 + (lane&15)][ko];
      }
      #pragma unroll
      for(int mi=0;mi<4;mi++)
        #pragma unroll
        for(int ni=0;ni<4;ni++)
          acc[mi][ni] = __builtin_amdgcn_mfma_f32_16x16x32_bf16(a[mi],b[ni],acc[mi][ni],0,0,0);
    }
    __syncthreads();
  }
  int r0 = (lane>>4)*4, c0 = lane&15;
  for(int mi=0;mi<4;mi++) for(int ni=0;ni<4;ni++){
    int row = mP + wm + mi*16 + r0, col = nP + wn + ni*16 + c0;
    #pragma unroll
    for(int r=0;r<4;r++) x2pre[(size_t)(row+r)*512 + col] = f2b(acc[mi][ni][r]);
  }
}

// ---------------- img-branch finish: LN/silu, w_ims, pstoch/pm/ps -----------
__global__ __launch_bounds__(256) void k_imgpost(const short* __restrict__ x2pre,
    const float* __restrict__ og, const float* __restrict__ ob,
    const float* __restrict__ w_ims, const float* __restrict__ b_ims,
    const float* __restrict__ eps_prior, float* __restrict__ out){
  int tid = threadIdx.x;
  int g = tid>>5, l = tid&31;
  int rbase = blockIdx.x*8;
  __shared__ float x2[8][512]; __shared__ float sl[8][64];
  int row = rbase + g;
  float vals[16]; float s=0.f, sq=0.f;
  #pragma unroll
  for(int i=0;i<16;i++){
    int k = l + i*32;
    float v = b2f(x2pre[(size_t)row*512+k]);
    vals[i] = v; s += v; sq += v*v;
  }
  #pragma unroll
  for(int m=1;m<32;m<<=1){ s += __shfl_xor(s, m); sq += __shfl_xor(sq, m); }
  float mu = s/512.f, var = sq/512.f - mu*mu;
  float rstd = rsqrtf(var + 1e-3f);
  #pragma unroll
  for(int i=0;i<16;i++){
    int k = l + i*32;
    float xn = (vals[i]-mu)*rstd*og[k]+ob[k];
    x2[g][k] = xn/(1.f+expf(-xn));
  }
  __syncthreads();
  { int q = tid>>6, n = tid&63;
    float a0=0.f, a1=0.f;
    for(int k=0;k<512;k++){
      float w = w_ims[k*64+n];
      a0 += x2[q][k]*w; a1 += x2[q+4][k]*w;
    }
    sl[q][n]=a0; sl[q+4][n]=a1; }
  __syncthreads();
  { int r = tid>>5, n = tid&31; int rw = rbase + r;
    float pm = sl[r][n] + b_ims[n];
    float psd = softplusf_(sl[r][n+32] + b_ims[n+32]) + 0.1f;
    float ep = eps_prior[(size_t)rw*32+n];
    size_t base = (size_t)rw*704;
    out[base+96+n] = pm + psd*ep; out[base+128+n] = pm; out[base+160+n] = psd; }
}

extern "C" void kernel_launch(void* const* d_in, const int* in_sizes, int n_in,
                              void* d_out, int out_size, void* d_ws, size_t ws_size,
                              hipStream_t stream) {
  const float* embed     = (const float*)d_in[0];
  const float* action    = (const float*)d_in[1];
  const float* is_first  = (const float*)d_in[2];
  const float* eps_prior = (const float*)d_in[3];
  const float* eps_post  = (const float*)d_in[4];
  const float* W_init    = (const float*)d_in[5];
  const float* w_in      = (const float*)d_in[6];
  const float* ln_in_g   = (const float*)d_in[7];
  const float* ln_in_b   = (const float*)d_in[8];
  const float* w_gru     = (const float*)d_in[9];
  const float* ln_gru_g  = (const float*)d_in[10];
  const float* ln_gru_b  = (const float*)d_in[11];
  const float* w_out     = (const float*)d_in[12];
  const float* ln_out_g  = (const float*)d_in[13];
  const float* ln_out_b  = (const float*)d_in[14];
  const float* w_ims     = (const float*)d_in[15];
  const float* b_ims     = (const float*)d_in[16];
  const float* w_obs     = (const float*)d_in[17];
  const float* ln_obs_g  = (const float*)d_in[18];
  const float* ln_obs_b  = (const float*)d_in[19];
  const float* w_ostat   = (const float*)d_in[20];
  const float* b_ostat   = (const float*)d_in[21];
  float* out = (float*)d_out;
  char* ws = (char*)d_ws;

  short* wgruT  = (short*)(ws + 0);           // 3,145,728
  short* wobsDT = (short*)(ws + 3145728);     //   524,288
  short* wobsET = (short*)(ws + 3670016);     // 1,048,576
  short* woutT  = (short*)(ws + 4718592);     //   524,288
  float* deter0 = (float*)(ws + 5242880);     //     2,048
  float* stoch0 = (float*)(ws + 5244928);     //       256
  short* xdeter = (short*)(ws + 5245184);     // 1,048,576
  float* deterF = (float*)(ws + 6293760);     // 1,048,576
  short* deterB = (short*)(ws + 7342336);     //   524,288
  float* parts  = (float*)(ws + 7866624);     // 3,145,728 (512x1536 f32)
  float* xopreP = (float*)(ws + 11012352);    // 3,145,728 (3x512x512 f32)
  short* x2pre  = (short*)(ws + 7866624);     // 33,554,432 — aliases parts/xopreP (epilogue only)
  // peak ws ≈ 41.4 MB (proven fits)

  dim3 blk(256);
  hipLaunchKernelGGL(k_wt, dim3(10240), blk, 0, stream,
                     w_gru, w_obs, w_out, wgruT, wobsDT, wobsET, woutT);
  hipLaunchKernelGGL(k_init, dim3(1), dim3(512), 0, stream,
                     W_init, w_out, ln_out_g, ln_out_b, w_ims, b_ims, deter0, stoch0);
  hipLaunchKernelGGL(k_x0, dim3(512), blk, 0, stream,
                     action, is_first, w_in, ln_in_g, ln_in_b, deter0, stoch0, xdeter, deterF);

  void* args[] = {
    (void*)&xdeter, (void*)&wgruT, (void*)&parts,
    (void*)&ln_gru_g, (void*)&ln_gru_b,
    (void*)&is_first, (void*)&deter0, (void*)&deterF, (void*)&deterB,
    (void*)&wobsDT, (void*)&wobsET, (void*)&embed, (void*)&xopreP,
    (void*)&ln_obs_g, (void*)&ln_obs_b, (void*)&w_ostat, (void*)&b_ostat,
    (void*)&eps_post, (void*)&action, (void*)&w_in,
    (void*)&ln_in_g, (void*)&ln_in_b, (void*)&stoch0, (void*)&out
  };
  hipError_t cerr = hipLaunchCooperativeKernel((void*)k_scan, dim3(256), dim3(256),
                                               args, 0, stream);
  if(cerr != hipSuccess){
    (void)hipGetLastError();  // clear sticky error, fall back to per-step launches
    for(int t=0; t<64; t++){
      hipLaunchKernelGGL(k_p1, dim3(192), blk, 0, stream, xdeter, wgruT, parts);
      hipLaunchKernelGGL(k_p2, dim3(512), blk, 0, stream,
                         parts, ln_gru_g, ln_gru_b, is_first, deter0, deterF, deterB, out, t);
      hipLaunchKernelGGL(k_p3, dim3(192), blk, 0, stream,
                         deterB, embed, wobsDT, wobsET, xopreP, t);
      hipLaunchKernelGGL(k_p4, dim3(512), blk, 0, stream,
                         xopreP, ln_obs_g, ln_obs_b, w_ostat, b_ostat, eps_post, is_first,
                         action, w_in, ln_in_g, ln_in_b, stoch0, deter0, deterF, xdeter, out, t);
    }
  }

  hipLaunchKernelGGL(k_img, dim3(256,4), blk, 0, stream, out, woutT, x2pre);
  hipLaunchKernelGGL(k_imgpost, dim3(4096), blk, 0, stream,
                     x2pre, ln_out_g, ln_out_b, w_ims, b_ims, eps_prior, out);
}

// Round 4
// 8561.227 us; speedup vs baseline: 2.2606x; 2.2606x over previous
//
#include <hip/hip_runtime.h>
#include <hip/hip_bf16.h>

// RSSM scan: B=512, T=64, STOCH=32, DETER=512, HIDDEN=512, ACT=12, EMBED=1024
// out per (b,t): [ostoch32, om32, ostd32, pstoch32, pm32, ps32, deter512] = 704 f32
// Strategy: 32 independent blocks, each owns 16 batch rows for the entire
// 64-step scan. No grid sync. Weights in L2, MFMA-fragment-linear bf16.

typedef __attribute__((ext_vector_type(8))) short bf16x8;
typedef __attribute__((ext_vector_type(4))) float f32x4;

static __device__ __forceinline__ short f2b(float x){
  __hip_bfloat16 h = __float2bfloat16(x);
  return *reinterpret_cast<short*>(&h);
}
static __device__ __forceinline__ float b2f(short s){
  __hip_bfloat16 h = *reinterpret_cast<__hip_bfloat16*>(&s);
  return __bfloat162float(h);
}
static __device__ __forceinline__ float softplusf_(float x){
  return (x > 20.f) ? x : log1pf(expf(x));
}
static __device__ __forceinline__ float sigm(float x){ return 1.f/(1.f+expf(-x)); }

// ---------------- weight convert (one-time): MFMA-fragment-linear layouts ----
// frag idx for [Ncols][K]: value(nt,ks,l,e) = W[k][n], k=ks*32+(l>>4)*8+e,
// n=nt*16+(l&15); linear = ((nt*NKS+ks)*64+l)*8+e
__global__ __launch_bounds__(256) void k_wt(
    const float* __restrict__ wi, const float* __restrict__ wg,
    const float* __restrict__ wo, const float* __restrict__ wst,
    const float* __restrict__ wou,
    short* __restrict__ WinT, short* __restrict__ WgruT,
    short* __restrict__ WobsT, short* __restrict__ WostatT,
    short* __restrict__ WoutT){
  int i = blockIdx.x*256 + threadIdx.x;
  if(i < 32768){ // w_in: N=512 (32 nt), K=64 (NKS=2), real K=44
    int e=i&7, l=(i>>3)&63, f=i>>9; int ks=f&1, nt=f>>1;
    int k=ks*32+((l>>4))*8+e, n=nt*16+(l&15);
    WinT[i] = (k<44)? f2b(wi[k*512+n]) : (short)0;
    return;
  }
  i -= 32768;
  if(i < 1572864){ // w_gru: N=1536 (96 nt), K=1024 (NKS=32)
    int e=i&7, l=(i>>3)&63, f=i>>9; int ks=f&31, nt=f>>5;
    int k=ks*32+((l>>4))*8+e, n=nt*16+(l&15);
    WgruT[i] = f2b(wg[k*1536+n]);
    return;
  }
  i -= 1572864;
  if(i < 786432){ // w_obs: N=512 (32 nt), K=1536 (NKS=48)
    int e=i&7, l=(i>>3)&63, f=i>>9; int ks=f%48, nt=f/48;
    int k=ks*32+((l>>4))*8+e, n=nt*16+(l&15);
    WobsT[i] = f2b(wo[k*512+n]);
    return;
  }
  i -= 786432;
  if(i < 32768){ // w_ostat: N=64 (4 nt), K=512 (NKS=16)
    int e=i&7, l=(i>>3)&63, f=i>>9; int ks=f&15, nt=f>>4;
    int k=ks*32+((l>>4))*8+e, n=nt*16+(l&15);
    WostatT[i] = f2b(wst[k*64+n]);
    return;
  }
  i -= 32768;
  { int n=i>>9, k=i&511; WoutT[i] = f2b(wou[k*512+n]); } // w_out row-major [n][k]
}

// ---------------- init: deter0 = tanh(W_init); stoch0 = img_mean(deter0) -----
__global__ __launch_bounds__(512) void k_init(const float* __restrict__ W_init,
    const float* __restrict__ w_out, const float* __restrict__ og, const float* __restrict__ ob,
    const float* __restrict__ w_ims, const float* __restrict__ b_ims,
    float* __restrict__ deter0, float* __restrict__ stoch0){
  __shared__ float d0[512]; __shared__ float red[512]; __shared__ float x2[512];
  int tid = threadIdx.x;
  float d = tanhf(W_init[tid]); d0[tid] = d; deter0[tid] = d; __syncthreads();
  float s = 0.f;
  for(int k=0;k<512;k++) s += d0[k]*w_out[k*512+tid];
  red[tid] = s; __syncthreads();
  for(int ss=256; ss>0; ss>>=1){ if(tid<ss) red[tid]+=red[tid+ss]; __syncthreads(); }
  float sum = red[0]; __syncthreads();
  red[tid] = s*s; __syncthreads();
  for(int ss=256; ss>0; ss>>=1){ if(tid<ss) red[tid]+=red[tid+ss]; __syncthreads(); }
  float sq = red[0];
  float mu = sum/512.f, var = sq/512.f - mu*mu;
  float rstd = rsqrtf(var + 1e-3f);
  float xn = (s-mu)*rstd*og[tid] + ob[tid];
  float xs = xn*sigm(xn);
  x2[tid] = xs; __syncthreads();
  if(tid < 32){
    float acc = b_ims[tid];
    for(int k=0;k<512;k++) acc += x2[k]*w_ims[k*64+tid];
    stoch0[tid] = acc;
  }
}

// ---------------- the scan: 32 blocks x 1024 threads, block g owns rows
// b = g*16 .. g*16+15 for all 64 steps. Only __syncthreads inside. ----------
__global__ __launch_bounds__(1024, 4) void k_scan(
    const float* __restrict__ embed, const float* __restrict__ action,
    const float* __restrict__ isf, const float* __restrict__ eps_post,
    const short* __restrict__ WinT, const float* __restrict__ ig, const float* __restrict__ ib,
    const short* __restrict__ WgruT, const float* __restrict__ gg, const float* __restrict__ gb,
    const short* __restrict__ WobsT, const float* __restrict__ og, const float* __restrict__ ob,
    const short* __restrict__ WostatT, const float* __restrict__ b_ostat,
    const float* __restrict__ deter0, const float* __restrict__ stoch0,
    float* __restrict__ out)
{
  // regB byte budget 49,408: xd bf16[16][1032] / parts bf16[16][1544] /
  // embB bf16[16][1032] / xo f32[16][520]
  __shared__ __align__(16) short RB[16*1544];
  __shared__ float deterS[16][516];   // masked deter / deter_n state (f32)
  __shared__ short dB[16][520];       // deter_n bf16 (obs A), then xo bf16 (ostat A)
  __shared__ short xrow[16][72];      // [stoch,a,pad] bf16
  __shared__ float stochS[16][32];    // raw ostoch carry
  __shared__ float sol[16][64];       // ostat GEMM out
  __shared__ float sumA[16], sqA[16]; // LN stats scratch
  __shared__ float fr[16];            // is_first per row
  __shared__ float d0s[512]; __shared__ float s0s[32];

  const int g = blockIdx.x, tid = threadIdx.x;
  const int w = tid>>6, lane = tid&63;
  const int col0 = lane&15, rg4 = (lane>>4)*4;
  float* xoF = (float*)RB;

  // ---- init state ----
  if(tid < 512) d0s[tid] = deter0[tid];
  if(tid < 32)  s0s[tid] = stoch0[tid];
  __syncthreads();
  { int r = tid>>6, kb = (tid&63)*8;
    #pragma unroll
    for(int i=0;i<8;i++) deterS[r][kb+i] = d0s[kb+i]; }
  if(tid < 512){ int r=tid>>5, c=tid&31; stochS[r][c] = s0s[c]; }
  __syncthreads();

  for(int t=0; t<64; t++){
    // ---- S0a: load is_first, zero stats ----
    if(tid < 16){ fr[tid] = isf[(g*16+tid)*64 + t]; sumA[tid]=0.f; sqA[tid]=0.f; }
    __syncthreads();
    // ---- S0b: mask stoch/action -> xrow; mask deter -> deterS + xd[512:1024] ----
    if(tid < 512){
      int r = tid>>5, c = tid&31; float f = fr[r];
      float sm = stochS[r][c]*(1.f-f) + s0s[c]*f;
      xrow[r][c] = f2b(sm);
      if(c < 12){
        float av = action[((size_t)(g*16+r)*64+t)*12 + c]*(1.f-f);
        xrow[r][32+c] = f2b(av);
      }
      if(c >= 12) xrow[r][32+c] = 0; // cols 44..63 zero pad
    }
    { int r = tid>>6, kb = (tid&63)*8; float f = fr[r];
      #pragma unroll
      for(int i=0;i<8;i++){
        int k = kb+i;
        float dm = deterS[r][k]*(1.f-f) + d0s[k]*f;
        deterS[r][k] = dm;
        RB[r*1032 + 512 + k] = f2b(dm);
      } }
    __syncthreads();
    // ---- S1: x_pre = xrow @ w_in (MFMA), raw bf16 -> xd[0:512], stats ----
    {
      f32x4 acc[2] = {};
      #pragma unroll
      for(int ks=0; ks<2; ks++){
        bf16x8 a = *(const bf16x8*)&xrow[col0][ks*32 + (lane>>4)*8];
        #pragma unroll
        for(int j=0;j<2;j++){
          int nt = w*2+j;
          bf16x8 b = *(const bf16x8*)&WinT[((nt*2 + ks)*64 + lane)*8];
          acc[j] = __builtin_amdgcn_mfma_f32_16x16x32_bf16(a,b,acc[j],0,0,0);
        }
      }
      float s[4]={0,0,0,0}, q[4]={0,0,0,0};
      #pragma unroll
      for(int j=0;j<2;j++){
        int col = (w*2+j)*16 + col0;
        #pragma unroll
        for(int r=0;r<4;r++){
          float v = acc[j][r];
          RB[(rg4+r)*1032 + col] = f2b(v);
          s[r]+=v; q[r]+=v*v;
        }
      }
      #pragma unroll
      for(int r=0;r<4;r++){
        #pragma unroll
        for(int m=1;m<16;m<<=1){ s[r]+=__shfl_xor(s[r],m); q[r]+=__shfl_xor(q[r],m); }
      }
      if(col0==0){
        #pragma unroll
        for(int r=0;r<4;r++){ atomicAdd(&sumA[rg4+r], s[r]); atomicAdd(&sqA[rg4+r], q[r]); }
      }
    }
    __syncthreads();
    // ---- S2: LN+silu x in place (xd[0:512]) ----
    {
      int r = tid>>6, kb = tid&63;
      float mu = sumA[r]/512.f, var = sqA[r]/512.f - mu*mu;
      float rstd = rsqrtf(var + 1e-3f);
      #pragma unroll
      for(int i=0;i<8;i++){
        int k = kb + i*64;
        float v = b2f(RB[r*1032 + k]);
        float xn = (v-mu)*rstd*ig[k] + ib[k];
        RB[r*1032 + k] = f2b(xn*sigm(xn));
      }
    }
    __syncthreads();
    // ---- S3: parts = xd @ w_gru (per wave 6 n-tiles, K=1024) ----
    {
      // re-zero stats for gru LN (consumed by S2 already)
      if(tid < 16){ sumA[tid]=0.f; sqA[tid]=0.f; }
      f32x4 acc[6] = {};
      const short* xdA = &RB[col0*1032 + (lane>>4)*8];
      for(int ks=0; ks<32; ks++){
        bf16x8 a = *(const bf16x8*)(xdA + ks*32);
        #pragma unroll
        for(int j=0;j<6;j++){
          bf16x8 b = *(const bf16x8*)&WgruT[((size_t)((w*6+j)*32 + ks)*64 + lane)*8];
          acc[j] = __builtin_amdgcn_mfma_f32_16x16x32_bf16(a,b,acc[j],0,0,0);
        }
      }
      __syncthreads();  // all xd reads done before parts overwrite
      float s[4]={0,0,0,0}, q[4]={0,0,0,0};
      #pragma unroll
      for(int j=0;j<6;j++){
        int col = (w*6+j)*16 + col0;
        #pragma unroll
        for(int r=0;r<4;r++){
          float v = acc[j][r];
          RB[(rg4+r)*1544 + col] = f2b(v);
          s[r]+=v; q[r]+=v*v;
        }
      }
      #pragma unroll
      for(int r=0;r<4;r++){
        #pragma unroll
        for(int m=1;m<16;m<<=1){ s[r]+=__shfl_xor(s[r],m); q[r]+=__shfl_xor(q[r],m); }
      }
      if(col0==0){
        #pragma unroll
        for(int r=0;r<4;r++){ atomicAdd(&sumA[rg4+r], s[r]); atomicAdd(&sqA[rg4+r], q[r]); }
      }
    }
    __syncthreads();
    // ---- S4: gates: LN(1536) + GRU update -> deterS, dB, out ----
    {
      int r = tid>>6, jb = tid&63;
      float mu = sumA[r]/1536.f, var = sqA[r]/1536.f - mu*mu;
      float rstd = rsqrtf(var + 1e-3f);
      size_t obase = (size_t)(g*16+r)*45056 + (size_t)t*704 + 192;
      #pragma unroll
      for(int i=0;i<8;i++){
        int j = jb + i*64;
        float xr = (b2f(RB[r*1544 + j      ])-mu)*rstd*gg[j]      + gb[j];
        float xc = (b2f(RB[r*1544 + 512 + j])-mu)*rstd*gg[512+j]  + gb[512+j];
        float xu = (b2f(RB[r*1544 + 1024+ j])-mu)*rstd*gg[1024+j] + gb[1024+j];
        float rr = sigm(xr);
        float cc = tanhf(rr*xc);
        float uu = sigm(xu-1.f);
        float dp = deterS[r][j];
        float dn = uu*cc + (1.f-uu)*dp;
        deterS[r][j] = dn;
        dB[r][j] = f2b(dn);
        out[obase + j] = dn;
      }
    }
    __syncthreads();
    // ---- S5: stage embed -> embB (RB), zero stats for obs LN ----
    if(tid < 16){ sumA[tid]=0.f; sqA[tid]=0.f; }
    {
      int r = tid>>6, kb = (tid&63)*16;
      const float4* ep = (const float4*)&embed[((size_t)(g*16+r)*64+t)*1024 + kb];
      #pragma unroll
      for(int v4=0; v4<4; v4++){
        float4 e = ep[v4];
        RB[r*1032 + kb + v4*4 + 0] = f2b(e.x);
        RB[r*1032 + kb + v4*4 + 1] = f2b(e.y);
        RB[r*1032 + kb + v4*4 + 2] = f2b(e.z);
        RB[r*1032 + kb + v4*4 + 3] = f2b(e.w);
      }
    }
    __syncthreads();
    // ---- S6: xo_pre = [deter_n | embed] @ w_obs (per wave 2 nt, K=1536) ----
    {
      f32x4 acc[2] = {};
      for(int ks=0; ks<16; ks++){
        bf16x8 a = *(const bf16x8*)&dB[col0][ks*32 + (lane>>4)*8];
        #pragma unroll
        for(int j=0;j<2;j++){
          bf16x8 b = *(const bf16x8*)&WobsT[((size_t)((w*2+j)*48 + ks)*64 + lane)*8];
          acc[j] = __builtin_amdgcn_mfma_f32_16x16x32_bf16(a,b,acc[j],0,0,0);
        }
      }
      for(int ks=16; ks<48; ks++){
        bf16x8 a = *(const bf16x8*)&RB[col0*1032 + (ks-16)*32 + (lane>>4)*8];
        #pragma unroll
        for(int j=0;j<2;j++){
          bf16x8 b = *(const bf16x8*)&WobsT[((size_t)((w*2+j)*48 + ks)*64 + lane)*8];
          acc[j] = __builtin_amdgcn_mfma_f32_16x16x32_bf16(a,b,acc[j],0,0,0);
        }
      }
      __syncthreads();  // embB reads done before xo overwrite
      float s[4]={0,0,0,0}, q[4]={0,0,0,0};
      #pragma unroll
      for(int j=0;j<2;j++){
        int col = (w*2+j)*16 + col0;
        #pragma unroll
        for(int r=0;r<4;r++){
          float v = acc[j][r];
          xoF[(rg4+r)*520 + col] = v;
          s[r]+=v; q[r]+=v*v;
        }
      }
      #pragma unroll
      for(int r=0;r<4;r++){
        #pragma unroll
        for(int m=1;m<16;m<<=1){ s[r]+=__shfl_xor(s[r],m); q[r]+=__shfl_xor(q[r],m); }
      }
      if(col0==0){
        #pragma unroll
        for(int r=0;r<4;r++){ atomicAdd(&sumA[rg4+r], s[r]); atomicAdd(&sqA[rg4+r], q[r]); }
      }
    }
    __syncthreads();
    // ---- S7: LN+silu xo -> dB (bf16) ----
    {
      int r = tid>>6, kb = tid&63;
      float mu = sumA[r]/512.f, var = sqA[r]/512.f - mu*mu;
      float rstd = rsqrtf(var + 1e-3f);
      #pragma unroll
      for(int i=0;i<8;i++){
        int k = kb + i*64;
        float v = xoF[r*520 + k];
        float xn = (v-mu)*rstd*og[k] + ob[k];
        dB[r][k] = f2b(xn*sigm(xn));
      }
    }
    __syncthreads();
    // ---- S8: so = xo @ w_ostat (waves 0..3, 1 nt each, K=512) ----
    if(w < 4){
      f32x4 acc = {};
      for(int ks=0; ks<16; ks++){
        bf16x8 a = *(const bf16x8*)&dB[col0][ks*32 + (lane>>4)*8];
        bf16x8 b = *(const bf16x8*)&WostatT[((w*16 + ks)*64 + lane)*8];
        acc = __builtin_amdgcn_mfma_f32_16x16x32_bf16(a,b,acc,0,0,0);
      }
      #pragma unroll
      for(int r=0;r<4;r++) sol[rg4+r][w*16+col0] = acc[r];
    }
    __syncthreads();
    // ---- S9: om/ostd/ostoch, write out, update stoch carry ----
    if(tid < 512){
      int r = tid>>5, c = tid&31;
      float om  = sol[r][c]    + b_ostat[c];
      float spi = sol[r][32+c] + b_ostat[32+c];
      float osd = softplusf_(spi) + 0.1f;
      float eo  = eps_post[((size_t)(g*16+r)*64+t)*32 + c];
      float ost = om + osd*eo;
      size_t base = (size_t)(g*16+r)*45056 + (size_t)t*704;
      out[base+c] = ost; out[base+32+c] = om; out[base+64+c] = osd;
      stochS[r][c] = ost;
    }
    __syncthreads();
  }
}

// ---------------- deferred img-branch GEMM: x2pre = deter_all @ w_out --------
__global__ __launch_bounds__(256) void k_img(const float* __restrict__ outp,
    const short* __restrict__ WoT, short* __restrict__ x2pre){
  __shared__ __align__(16) short As[128][72];
  __shared__ __align__(16) short Bs[128][72];
  int tid = threadIdx.x, lane = tid&63, wid = tid>>6;
  int wm = (wid>>1)*64, wn = (wid&1)*64;
  int mP = blockIdx.x*128, nP = blockIdx.y*128;
  f32x4 acc[4][4] = {};
  for(int kt=0; kt<512; kt+=64){
    #pragma unroll
    for(int c=0;c<4;c++){
      int idx = tid + c*256; int r = idx>>3, kc = (idx&7)*8;
      const float* src = &outp[(size_t)(mP+r)*704 + 192 + kt + kc];
      float4 f0 = *reinterpret_cast<const float4*>(src);
      float4 f1 = *reinterpret_cast<const float4*>(src+4);
      bf16x8 v;
      v[0]=f2b(f0.x); v[1]=f2b(f0.y); v[2]=f2b(f0.z); v[3]=f2b(f0.w);
      v[4]=f2b(f1.x); v[5]=f2b(f1.y); v[6]=f2b(f1.z); v[7]=f2b(f1.w);
      *reinterpret_cast<bf16x8*>(&As[r][kc]) = v;
      *(int4*)&Bs[r][kc] = *(const int4*)&WoT[(nP+r)*512 + kt + kc];
    }
    __syncthreads();
    #pragma unroll
    for(int ks=0; ks<64; ks+=32){
      int ko = ks + 8*(lane>>4);
      bf16x8 a[4], b[4];
      #pragma unroll
      for(int i=0;i<4;i++){
        a[i] = *(const bf16x8*)&As[wm + i*16 + (lane&15)][ko];
        b[i] = *(const bf16x8*)&Bs[wn + i*16 + (lane&15)][ko];
      }
      #pragma unroll
      for(int mi=0;mi<4;mi++)
        #pragma unroll
        for(int ni=0;ni<4;ni++)
          acc[mi][ni] = __builtin_amdgcn_mfma_f32_16x16x32_bf16(a[mi],b[ni],acc[mi][ni],0,0,0);
    }
    __syncthreads();
  }
  int r0 = (lane>>4)*4, c0 = lane&15;
  for(int mi=0;mi<4;mi++) for(int ni=0;ni<4;ni++){
    int row = mP + wm + mi*16 + r0, col = nP + wn + ni*16 + c0;
    #pragma unroll
    for(int r=0;r<4;r++) x2pre[(size_t)(row+r)*512 + col] = f2b(acc[mi][ni][r]);
  }
}

// ---------------- img-branch finish: LN/silu, w_ims, pstoch/pm/ps -----------
__global__ __launch_bounds__(256) void k_imgpost(const short* __restrict__ x2pre,
    const float* __restrict__ og, const float* __restrict__ ob,
    const float* __restrict__ w_ims, const float* __restrict__ b_ims,
    const float* __restrict__ eps_prior, float* __restrict__ out){
  int tid = threadIdx.x;
  int g = tid>>5, l = tid&31;
  int rbase = blockIdx.x*8;
  __shared__ float x2[8][512]; __shared__ float sl[8][64];
  int row = rbase + g;
  float vals[16]; float s=0.f, sq=0.f;
  #pragma unroll
  for(int i=0;i<16;i++){
    int k = l + i*32;
    float v = b2f(x2pre[(size_t)row*512+k]);
    vals[i] = v; s += v; sq += v*v;
  }
  #pragma unroll
  for(int m=1;m<32;m<<=1){ s += __shfl_xor(s, m); sq += __shfl_xor(sq, m); }
  float mu = s/512.f, var = sq/512.f - mu*mu;
  float rstd = rsqrtf(var + 1e-3f);
  #pragma unroll
  for(int i=0;i<16;i++){
    int k = l + i*32;
    float xn = (vals[i]-mu)*rstd*og[k]+ob[k];
    x2[g][k] = xn/(1.f+expf(-xn));
  }
  __syncthreads();
  { int q = tid>>6, n = tid&63;
    float a0=0.f, a1=0.f;
    for(int k=0;k<512;k++){
      float w = w_ims[k*64+n];
      a0 += x2[q][k]*w; a1 += x2[q+4][k]*w;
    }
    sl[q][n]=a0; sl[q+4][n]=a1; }
  __syncthreads();
  { int r = tid>>5, n = tid&31; int rw = rbase + r;
    float pm = sl[r][n] + b_ims[n];
    float psd = softplusf_(sl[r][n+32] + b_ims[n+32]) + 0.1f;
    float ep = eps_prior[(size_t)rw*32+n];
    size_t base = (size_t)rw*704;
    out[base+96+n] = pm + psd*ep; out[base+128+n] = pm; out[base+160+n] = psd; }
}

extern "C" void kernel_launch(void* const* d_in, const int* in_sizes, int n_in,
                              void* d_out, int out_size, void* d_ws, size_t ws_size,
                              hipStream_t stream) {
  const float* embed     = (const float*)d_in[0];
  const float* action    = (const float*)d_in[1];
  const float* is_first  = (const float*)d_in[2];
  const float* eps_prior = (const float*)d_in[3];
  const float* eps_post  = (const float*)d_in[4];
  const float* W_init    = (const float*)d_in[5];
  const float* w_in      = (const float*)d_in[6];
  const float* ln_in_g   = (const float*)d_in[7];
  const float* ln_in_b   = (const float*)d_in[8];
  const float* w_gru     = (const float*)d_in[9];
  const float* ln_gru_g  = (const float*)d_in[10];
  const float* ln_gru_b  = (const float*)d_in[11];
  const float* w_out     = (const float*)d_in[12];
  const float* ln_out_g  = (const float*)d_in[13];
  const float* ln_out_b  = (const float*)d_in[14];
  const float* w_ims     = (const float*)d_in[15];
  const float* b_ims     = (const float*)d_in[16];
  const float* w_obs     = (const float*)d_in[17];
  const float* ln_obs_g  = (const float*)d_in[18];
  const float* ln_obs_b  = (const float*)d_in[19];
  const float* w_ostat   = (const float*)d_in[20];
  const float* b_ostat   = (const float*)d_in[21];
  float* out = (float*)d_out;
  char* ws = (char*)d_ws;

  short* WinT    = (short*)(ws + 0);         //    65,536
  short* WgruT   = (short*)(ws + 65536);     // 3,145,728
  short* WobsT   = (short*)(ws + 3211264);   // 1,572,864
  short* WostatT = (short*)(ws + 4784128);   //    65,536
  short* WoutT   = (short*)(ws + 4849664);   //   524,288
  float* deter0  = (float*)(ws + 5373952);   //     2,048
  float* stoch0  = (float*)(ws + 5376000);   //       256
  short* x2pre   = (short*)(ws + 5376256);   // 33,554,432
  // total ws use ≈ 38.9 MB

  dim3 blk(256);
  hipLaunchKernelGGL(k_wt, dim3(10496), blk, 0, stream,
                     w_in, w_gru, w_obs, w_ostat, w_out,
                     WinT, WgruT, WobsT, WostatT, WoutT);
  hipLaunchKernelGGL(k_init, dim3(1), dim3(512), 0, stream,
                     W_init, w_out, ln_out_g, ln_out_b, w_ims, b_ims, deter0, stoch0);
  hipLaunchKernelGGL(k_scan, dim3(32), dim3(1024), 0, stream,
                     embed, action, is_first, eps_post,
                     WinT, ln_in_g, ln_in_b,
                     WgruT, ln_gru_g, ln_gru_b,
                     WobsT, ln_obs_g, ln_obs_b,
                     WostatT, b_ostat,
                     deter0, stoch0, out);
  hipLaunchKernelGGL(k_img, dim3(256,4), blk, 0, stream, out, WoutT, x2pre);
  hipLaunchKernelGGL(k_imgpost, dim3(4096), blk, 0, stream,
                     x2pre, ln_out_g, ln_out_b, w_ims, b_ims, eps_prior, out);
}